// Round 2
// baseline (212.858 us; speedup 1.0000x reference)
//
#include <hip/hip_runtime.h>
#include <stdint.h>

// ---------------- modular arithmetic ----------------
static constexpr uint32_t P = 2013265921u;         // 15*2^27 + 1
static constexpr int      LOGM = 11;               // per-block DFT size 2048
static constexpr int      MSZ  = 1 << LOGM;

__host__ __device__ constexpr uint32_t neg_pinv32() {
    uint32_t x = 1u;
    for (int i = 0; i < 5; ++i) x *= 2u - P * x;
    return 0u - x;
}
static constexpr uint32_t NEG_PINV = neg_pinv32();
static constexpr uint32_t R1 = (uint32_t)(((uint64_t)1 << 32) % P);
static constexpr uint32_t R2 = (uint32_t)(((uint64_t)R1 * R1) % P);

// Montgomery (R=2^32). mont_mul(plain, Mont(w)) = plain*w  — used for the
// epilogue twiddle chains, phase-0, and phase-3 butterflies.
__device__ __forceinline__ uint32_t mont_mul(uint32_t a, uint32_t b) {
    uint32_t tlo = a * b;
    uint32_t thi = __umulhi(a, b);
    uint32_t m   = tlo * NEG_PINV;
    uint32_t r   = thi + __umulhi(m, P) + (tlo != 0u);   // r < 2P
    uint32_t s   = r - P;
    return s < r ? s : r;
}
__device__ __forceinline__ uint32_t to_mont(uint32_t a) { return mont_mul(a, R2); }

// Shoup mult by precomputed (w, w'=floor(w*2^32/P)): 4 ops + 2-op reduce.
__device__ __forceinline__ uint32_t shoup_mul(uint32_t w, uint32_t wp, uint32_t x) {
    uint32_t q = __umulhi(wp, x);
    uint32_t t = w * x - q * P;          // exact: t in [0, 2P) < 2^32
    uint32_t s = t - P;
    return s < t ? s : t;
}
__device__ __forceinline__ uint32_t add_p(uint32_t a, uint32_t b) {
    uint32_t r = a + b, s = r - P; return s < r ? s : r;
}
__device__ __forceinline__ uint32_t sub_p(uint32_t a, uint32_t b) {
    uint32_t r = a - b, s = r + P; return s < r ? s : r;
}
__device__ __forceinline__ uint4 mm4(uint32_t w, uint4 v) {   // Montgomery x4
    return make_uint4(mont_mul(w, v.x), mont_mul(w, v.y),
                      mont_mul(w, v.z), mont_mul(w, v.w));
}
// butterfly variants (all keep values canonical [0,P))
__device__ __forceinline__ void bf4_sh(uint4& L, uint4& H, uint2 w) {
    uint4 t = make_uint4(shoup_mul(w.x, w.y, H.x), shoup_mul(w.x, w.y, H.y),
                         shoup_mul(w.x, w.y, H.z), shoup_mul(w.x, w.y, H.w));
    uint4 l = L;
    L = make_uint4(add_p(l.x, t.x), add_p(l.y, t.y), add_p(l.z, t.z), add_p(l.w, t.w));
    H = make_uint4(sub_p(l.x, t.x), sub_p(l.y, t.y), sub_p(l.z, t.z), sub_p(l.w, t.w));
}
__device__ __forceinline__ void bf4_mont(uint4& L, uint4& H, uint32_t wm) {
    uint4 t = mm4(wm, H);
    uint4 l = L;
    L = make_uint4(add_p(l.x, t.x), add_p(l.y, t.y), add_p(l.z, t.z), add_p(l.w, t.w));
    H = make_uint4(sub_p(l.x, t.x), sub_p(l.y, t.y), sub_p(l.z, t.z), sub_p(l.w, t.w));
}
__device__ __forceinline__ void bf4_triv(uint4& L, uint4& H) {   // w == 1
    uint4 l = L, h = H;
    L = make_uint4(add_p(l.x, h.x), add_p(l.y, h.y), add_p(l.z, h.z), add_p(l.w, h.w));
    H = make_uint4(sub_p(l.x, h.x), sub_p(l.y, h.y), sub_p(l.z, h.z), sub_p(l.w, h.w));
}

// LDS element swizzle: spreads b128 accesses evenly over the 8 bank-quads for
// the access sets of all 4 phases (strides 1/8/64/512) in the 1-col packing.
__device__ __forceinline__ int g_sw(int el) {
    return el ^ (((el >> 3) ^ (el >> 6)) & 7);
}

// 3 DIT stages (radix-8) with Shoup twiddles (phases 1-2).
__device__ __forceinline__ void radix8_sh(uint4 x[8],
        uint2 ta, uint2 tb0, uint2 tb1,
        uint2 tc0, uint2 tc1, uint2 tc2, uint2 tc3) {
    bf4_sh(x[0], x[1], ta);  bf4_sh(x[2], x[3], ta);
    bf4_sh(x[4], x[5], ta);  bf4_sh(x[6], x[7], ta);
    bf4_sh(x[0], x[2], tb0); bf4_sh(x[1], x[3], tb1);
    bf4_sh(x[4], x[6], tb0); bf4_sh(x[5], x[7], tb1);
    bf4_sh(x[0], x[4], tc0); bf4_sh(x[1], x[5], tc1);
    bf4_sh(x[2], x[6], tc2); bf4_sh(x[3], x[7], tc3);
}

// One block = 256 threads = one 2048-pt inverse DFT over ONE matrix column
// (each element uint4 = 4 batch columns).  sub = t owns 8 elements.
// LDS = 32 KiB buf + 4 KiB stab (stages 4-9) + 2 KiB mtab (Mont(W^lo)) ->
// ~39 KiB -> 4 independent blocks/CU (vs 2): four 4-wave barrier domains so
// one block's barrier drain / gather latency hides under the others' VALU.
// Phase-3 twiddles are derived from mtab: W^2lo = M^2, W^(lo+512) = M*W^512.
// The 16 B/lane global accesses rely on L2 merging across the 4 sibling
// column blocks (c quad 4g..4g+3), which the XCD swizzle keeps on one XCD
// launched <=24 bids apart (round-1 evidence: 32 B partials merged exactly).
template <bool PASS2>
__global__ __launch_bounds__(256, 4) void intt_pass(
        const uint4* __restrict__ src, uint4* __restrict__ dst,
        const uint32_t* __restrict__ tw,
        const uint32_t* __restrict__ ninv_p)
{
    __shared__ uint4    buf[MSZ];     // 32 KiB
    __shared__ uint2    stab[511];    // 4088 B (w, w_shoup); stage s at 2^(s-1)-1, s=4..9
    __shared__ uint32_t mtab[512];    // 2 KiB: Mont(W^lo), lo in [0,512)

    const int      t   = threadIdx.x;
    const int      sub = t;                // [0,256)
    const uint32_t bid = blockIdx.x;
    // XCD swizzle for 2048 blocks: bid&7 = XCD; column quad 4g..4g+3 lands on
    // one XCD at bids {k,k+8,k+16,k+24} -> co-resident -> L2 line merge.
    const uint32_t c   = ((bid & 7u) << 8) | (bid >> 3);   // global matrix column

    // stage-twiddle table build (2 entries/thread): plain w + Shoup companion.
    // stab[2^(s-1)-1 + j] = W^(j*2^(11-s)), W = w^2048 -> tw[j << (21-(s-1))].
    uint32_t wv[2]; int ev[2];
#pragma unroll
    for (int q = 0; q < 2; ++q) {
        int e = t + (q << 8);
        ev[q] = e;
        if (e < 511) {
            uint32_t ep1 = (uint32_t)e + 1u;
            int sm1 = 31 - __clz((int)ep1);
            uint32_t j = ep1 - (1u << sm1);
            wv[q] = tw[j << (21 - sm1)];
        }
    }
    // mtab loads: W^lo = tw[lo << 11] (same 512 words for every block -> L2-hot)
    uint32_t mv0 = tw[(uint32_t)t << 11];
    uint32_t mv1 = tw[(uint32_t)(t + 256) << 11];

    // global gather, bit-reversal folded in: el = 8*sub+m <- row rev11(el)
    const uint32_t r8 = __brev((uint32_t)sub) >> 24;
    uint4 x[8];
#pragma unroll
    for (int m = 0; m < 8; ++m) {
        uint32_t r3 = __brev((uint32_t)m) >> 29;
        x[m] = src[((r3 << 8) | r8) * (uint32_t)MSZ + c];
    }

    // finish tables (64-bit div + Montgomery converts overlap gather latency)
#pragma unroll
    for (int q = 0; q < 2; ++q) {
        if (ev[q] < 511) {
            uint32_t w  = wv[q];
            uint32_t wp = (uint32_t)((((uint64_t)w) << 32) / P);
            stab[ev[q]] = make_uint2(w, wp);
        }
    }
    mtab[t]       = to_mont(mv0);
    mtab[t + 256] = to_mont(mv1);

    // phase-0 non-trivial twiddles (uniform): u1=W^512, u2=W^256, u3=W^768
    const uint32_t u1 = to_mont(tw[1u << 20]);
    const uint32_t u2 = to_mont(tw[1u << 19]);
    const uint32_t u3 = to_mont(tw[3u << 19]);

    // ---- phase 0: stages 1-3, j=0 group (7 of 12 butterflies are w=1) ----
    bf4_triv(x[0], x[1]);  bf4_triv(x[2], x[3]);
    bf4_triv(x[4], x[5]);  bf4_triv(x[6], x[7]);
    bf4_triv(x[0], x[2]);  bf4_mont(x[1], x[3], u1);
    bf4_triv(x[4], x[6]);  bf4_mont(x[5], x[7], u1);
    bf4_triv(x[0], x[4]);  bf4_mont(x[1], x[5], u2);
    bf4_mont(x[2], x[6], u1); bf4_mont(x[3], x[7], u3);
#pragma unroll
    for (int m = 0; m < 8; ++m) buf[g_sw(8 * sub + m)] = x[m];
    __syncthreads();   // covers stab, mtab AND phase-0 buf

    // ---- phase 1: stages 4-6 (element stride 8) ----
    {
        const int L = sub & 7, hi = sub >> 3;
        const int base = (hi << 6) | L;
#pragma unroll
        for (int m = 0; m < 8; ++m) x[m] = buf[g_sw(base | (m << 3))];
        radix8_sh(x, stab[7 + L], stab[15 + L], stab[23 + L],
                     stab[31 + L], stab[39 + L], stab[47 + L], stab[55 + L]);
#pragma unroll
        for (int m = 0; m < 8; ++m) buf[g_sw(base | (m << 3))] = x[m];
    }
    __syncthreads();

    // ---- phase 2: stages 7-9 (element stride 64) ----
    {
        const int L = sub & 63, hi = sub >> 6;
        const int base = (hi << 9) | L;
#pragma unroll
        for (int m = 0; m < 8; ++m) x[m] = buf[g_sw(base | (m << 6))];
        radix8_sh(x, stab[63 + L], stab[127 + L], stab[191 + L],
                     stab[255 + L], stab[319 + L], stab[383 + L], stab[447 + L]);
#pragma unroll
        for (int m = 0; m < 8; ++m) buf[g_sw(base | (m << 6))] = x[m];
    }
    __syncthreads();

    // ---- phase 3: stages 10-11 (stride 512) + epilogue ----
    // Twiddles from mtab: stage 10 uses W^(2lo) = M*M; stage 11 uses W^lo = M
    // and W^(lo+512) = M * u1  (u1 = Mont(W^512)).
    uint32_t nm = 0u, s256 = 0u, step512 = 0u, tm0 = 0u;
    if (PASS2) {
        nm = to_mont(*ninv_p);
    } else {
        s256    = to_mont(tw[c << 8]);              // Mont(w^(256c))
        step512 = mont_mul(s256, s256);             // Mont(w^(512c))
        tm0     = to_mont(tw[c * (uint32_t)sub]);   // Mont(w^(c*sub)), exp<2^19
    }
#pragma unroll
    for (int gg = 0; gg < 2; ++gg) {
        const int lo = sub + (gg << 8);             // [0,512)
        uint4 y[4];
#pragma unroll
        for (int m = 0; m < 4; ++m) y[m] = buf[g_sw(lo | (m << 9))];
        const uint32_t M    = mtab[lo];             // Mont(W^lo)
        const uint32_t t10  = mont_mul(M, M);       // Mont(W^(2lo))
        const uint32_t t111 = mont_mul(M, u1);      // Mont(W^(lo+512))
        bf4_mont(y[0], y[1], t10);  bf4_mont(y[2], y[3], t10);
        bf4_mont(y[0], y[2], M);    bf4_mont(y[1], y[3], t111);

        if (!PASS2) {
            uint32_t tm = tm0;                      // Mont(w^(c*lo))
#pragma unroll
            for (int m = 0; m < 4; ++m) {
                dst[c * (uint32_t)MSZ + (uint32_t)((m << 9) | lo)] = mm4(tm, y[m]);
                tm = mont_mul(tm, step512);
            }
            tm0 = mont_mul(tm0, s256);              // advance lo by 256
        } else {
#pragma unroll
            for (int m = 0; m < 4; ++m)
                dst[(uint32_t)((m << 9) | lo) * (uint32_t)MSZ + c] = mm4(nm, y[m]);
        }
    }
}

// ------------------------------- launch ------------------------------------
extern "C" void kernel_launch(void* const* d_in, const int* in_sizes, int n_in,
                              void* d_out, int out_size, void* d_ws, size_t ws_size,
                              hipStream_t stream)
{
    const uint4*    x    = (const uint4*)d_in[0];      // (N, 4) int32 rows
    const uint32_t* tw   = (const uint32_t*)d_in[1];   // w^k, k < 2^21
    const uint32_t* ninv = (const uint32_t*)d_in[2];
    uint4*          out  = (uint4*)d_out;

    intt_pass<false><<<dim3(2048), dim3(256), 0, stream>>>(x, out, tw, ninv);
    intt_pass<true ><<<dim3(2048), dim3(256), 0, stream>>>(out, out, tw, ninv);
}

// Round 3
// 205.384 us; speedup vs baseline: 1.0364x; 1.0364x over previous
//
#include <hip/hip_runtime.h>
#include <stdint.h>

// ---------------- modular arithmetic ----------------
static constexpr uint32_t P = 2013265921u;         // 15*2^27 + 1
static constexpr int      LOGM = 11;               // per-block DFT size 2048
static constexpr int      MSZ  = 1 << LOGM;
static constexpr int      NCOL = 2;                // matrix columns per block (each el = uint4 = 4 batch cols)

__host__ __device__ constexpr uint32_t neg_pinv32() {
    uint32_t x = 1u;
    for (int i = 0; i < 5; ++i) x *= 2u - P * x;
    return 0u - x;
}
static constexpr uint32_t NEG_PINV = neg_pinv32();
static constexpr uint32_t R1 = (uint32_t)(((uint64_t)1 << 32) % P);
static constexpr uint32_t R2 = (uint32_t)(((uint64_t)R1 * R1) % P);

// Montgomery (R=2^32). mont_mul(plain, Mont(w)) = plain*w.
__device__ __forceinline__ uint32_t mont_mul(uint32_t a, uint32_t b) {
    uint32_t tlo = a * b;
    uint32_t thi = __umulhi(a, b);
    uint32_t m   = tlo * NEG_PINV;
    uint32_t r   = thi + __umulhi(m, P) + (tlo != 0u);   // r < 2P
    uint32_t s   = r - P;
    return s < r ? s : r;
}
__device__ __forceinline__ uint32_t to_mont(uint32_t a) { return mont_mul(a, R2); }

// Shoup mult by precomputed (w, w'=floor(w*2^32/P)): 4 ops + 2-op reduce.
__device__ __forceinline__ uint32_t shoup_mul(uint32_t w, uint32_t wp, uint32_t x) {
    uint32_t q = __umulhi(wp, x);
    uint32_t t = w * x - q * P;          // exact: t in [0, 2P) < 2^32
    uint32_t s = t - P;
    return s < t ? s : t;
}
__device__ __forceinline__ uint32_t add_p(uint32_t a, uint32_t b) {
    uint32_t r = a + b, s = r - P; return s < r ? s : r;
}
__device__ __forceinline__ uint32_t sub_p(uint32_t a, uint32_t b) {
    uint32_t r = a - b, s = r + P; return s < r ? s : r;
}
__device__ __forceinline__ uint4 mm4(uint32_t w, uint4 v) {   // Montgomery x4
    return make_uint4(mont_mul(w, v.x), mont_mul(w, v.y),
                      mont_mul(w, v.z), mont_mul(w, v.w));
}
// butterfly variants (all keep values canonical [0,P))
__device__ __forceinline__ void bf4_sh(uint4& L, uint4& H, uint2 w) {
    uint4 t = make_uint4(shoup_mul(w.x, w.y, H.x), shoup_mul(w.x, w.y, H.y),
                         shoup_mul(w.x, w.y, H.z), shoup_mul(w.x, w.y, H.w));
    uint4 l = L;
    L = make_uint4(add_p(l.x, t.x), add_p(l.y, t.y), add_p(l.z, t.z), add_p(l.w, t.w));
    H = make_uint4(sub_p(l.x, t.x), sub_p(l.y, t.y), sub_p(l.z, t.z), sub_p(l.w, t.w));
}
__device__ __forceinline__ void bf4_mont(uint4& L, uint4& H, uint32_t wm) {
    uint4 t = mm4(wm, H);
    uint4 l = L;
    L = make_uint4(add_p(l.x, t.x), add_p(l.y, t.y), add_p(l.z, t.z), add_p(l.w, t.w));
    H = make_uint4(sub_p(l.x, t.x), sub_p(l.y, t.y), sub_p(l.z, t.z), sub_p(l.w, t.w));
}
__device__ __forceinline__ void bf4_triv(uint4& L, uint4& H) {   // w == 1
    uint4 l = L, h = H;
    L = make_uint4(add_p(l.x, h.x), add_p(l.y, h.y), add_p(l.z, h.z), add_p(l.w, h.w));
    H = make_uint4(sub_p(l.x, h.x), sub_p(l.y, h.y), sub_p(l.z, h.z), sub_p(l.w, h.w));
}

// LDS element swizzle: conflict-free for strides 1/8/64/512 in the 2-col
// packing (round-1 measured: SQ_LDS_BANK_CONFLICT == 0).
__device__ __forceinline__ int g_sw(int el) {
    return el ^ (((el >> 3) ^ (el >> 6)) & 7);
}
__device__ __forceinline__ int fidx(int el, int c4) { return (g_sw(el) << 1) | c4; }

// 3 DIT stages (radix-8) with Shoup twiddles (phases 1-2).
__device__ __forceinline__ void radix8_sh(uint4 x[8],
        uint2 ta, uint2 tb0, uint2 tb1,
        uint2 tc0, uint2 tc1, uint2 tc2, uint2 tc3) {
    bf4_sh(x[0], x[1], ta);  bf4_sh(x[2], x[3], ta);
    bf4_sh(x[4], x[5], ta);  bf4_sh(x[6], x[7], ta);
    bf4_sh(x[0], x[2], tb0); bf4_sh(x[1], x[3], tb1);
    bf4_sh(x[4], x[6], tb0); bf4_sh(x[5], x[7], tb1);
    bf4_sh(x[0], x[4], tc0); bf4_sh(x[1], x[5], tc1);
    bf4_sh(x[2], x[6], tc2); bf4_sh(x[3], x[7], tc3);
}

// Persistent-block layout: 512 blocks x 512 threads, each block = 2048-pt
// inverse DFT over 2 adjacent matrix columns, TWO column-groups per block
// (grp, grp+512).  c4 = t&1, sub = t>>1 owns 8 elements; 2 consecutive lanes
// = 32 B of each scattered global line (round-1 measured: L2 merges these).
// LDS = 64 KiB buf + 4 KiB stab (stages 4-9) + 2 KiB mtab = ~70 KiB ->
// 2 blocks/CU with headroom (round-1's 80 KiB was an exact fit -> marginal).
// Phase-3 twiddles derived from mtab (round-2-verified math):
//   W^(2lo) = M*M,  W^lo = M,  W^(lo+512) = M*u1,  M = Mont(W^lo).
// Iter-1's gather is prefetched into registers right AFTER the phase-2->3
// __syncthreads: a prefetch issued before a barrier would be drained by the
// barrier's implicit s_waitcnt vmcnt(0); issued after, the 8 loads overlap
// all of phase 3 (compute + scatter) and are complete by the loop-top sync.
// In-place pass 2 is safe: each column is read+written by exactly one
// (block, iter), and prefetched columns belong to the same block's iter 1.
template <bool PASS2>
__global__ __launch_bounds__(512, 4) void intt_pass(
        const uint4* __restrict__ src, uint4* __restrict__ dst,
        const uint32_t* __restrict__ tw,
        const uint32_t* __restrict__ ninv_p)
{
    __shared__ uint4    buf[MSZ * NCOL];  // 64 KiB
    __shared__ uint2    stab[511];        // 4088 B (w, w_shoup); stage s at 2^(s-1)-1, s<=9
    __shared__ uint32_t mtab[512];        // 2 KiB: Mont(W^lo), lo in [0,512)

    const int      t   = threadIdx.x;
    const int      c4  = t & 1;
    const int      sub = t >> 1;           // [0,256)
    const uint32_t bid = blockIdx.x;
    // XCD swizzle for 512 blocks: bid&7 = XCD; sibling blocks sharing a 64 B
    // line (grp 2g/2g+1) are 8 bids apart -> same XCD, co-resident.
    const uint32_t grp = ((bid & 7u) << 6) | (bid >> 3);   // [0,512)
    const uint32_t c0  = (grp << 1) | (uint32_t)c4;        // iter-0 column

    // table source loads (1 stab entry + 1 mtab entry per thread)
    uint32_t wv = 0u;
    if (t < 511) {
        uint32_t ep1 = (uint32_t)t + 1u;
        int sm1 = 31 - __clz((int)ep1);
        uint32_t j = ep1 - (1u << sm1);
        wv = tw[j << (21 - sm1)];          // W^(j*2^(11-s)) for stage s=sm1+1
    }
    uint32_t mv = tw[(uint32_t)t << 11];   // W^t  (W = w^2048)

    // iter-0 global gather, bit-reversal folded in: el = 8*sub+m <- row rev11(el)
    const uint32_t r8 = __brev((uint32_t)sub) >> 24;
    uint4 x[8];
#pragma unroll
    for (int m = 0; m < 8; ++m) {
        uint32_t r3 = __brev((uint32_t)m) >> 29;
        x[m] = src[((r3 << 8) | r8) * (uint32_t)MSZ + c0];
    }

    // finish tables (64-bit div + Montgomery convert overlap gather latency)
    if (t < 511) {
        uint32_t wp = (uint32_t)((((uint64_t)wv) << 32) / P);
        stab[t] = make_uint2(wv, wp);
    }
    mtab[t] = to_mont(mv);

    // phase-0 non-trivial twiddles (uniform): u1=W^512, u2=W^256, u3=W^768
    const uint32_t u1 = to_mont(tw[1u << 20]);
    const uint32_t u2 = to_mont(tw[1u << 19]);
    const uint32_t u3 = to_mont(tw[3u << 19]);
    uint32_t nm = 0u;
    if (PASS2) nm = to_mont(*ninv_p);

    uint4 xn[8];
#pragma unroll
    for (int it = 0; it < 2; ++it) {
        const uint32_t c = c0 + (uint32_t)(it << 10);
        if (it) {
            __syncthreads();               // phase-3 readers done before buf reuse
#pragma unroll
            for (int m = 0; m < 8; ++m) x[m] = xn[m];
        }

        // ---- phase 0: stages 1-3, j=0 group (7 of 12 butterflies are w=1) ----
        bf4_triv(x[0], x[1]);  bf4_triv(x[2], x[3]);
        bf4_triv(x[4], x[5]);  bf4_triv(x[6], x[7]);
        bf4_triv(x[0], x[2]);  bf4_mont(x[1], x[3], u1);
        bf4_triv(x[4], x[6]);  bf4_mont(x[5], x[7], u1);
        bf4_triv(x[0], x[4]);  bf4_mont(x[1], x[5], u2);
        bf4_mont(x[2], x[6], u1); bf4_mont(x[3], x[7], u3);
#pragma unroll
        for (int m = 0; m < 8; ++m) buf[fidx(8 * sub + m, c4)] = x[m];
        __syncthreads();   // covers tables (iter 0) AND phase-0 buf

        // ---- phase 1: stages 4-6 (element stride 8) ----
        {
            const int L = sub & 7, hi = sub >> 3;
            const int base = (hi << 6) | L;
#pragma unroll
            for (int m = 0; m < 8; ++m) x[m] = buf[fidx(base | (m << 3), c4)];
            radix8_sh(x, stab[7 + L], stab[15 + L], stab[23 + L],
                         stab[31 + L], stab[39 + L], stab[47 + L], stab[55 + L]);
#pragma unroll
            for (int m = 0; m < 8; ++m) buf[fidx(base | (m << 3), c4)] = x[m];
        }
        __syncthreads();

        // ---- phase 2: stages 7-9 (element stride 64) ----
        {
            const int L = sub & 63, hi = sub >> 6;
            const int base = (hi << 9) | L;
#pragma unroll
            for (int m = 0; m < 8; ++m) x[m] = buf[fidx(base | (m << 6), c4)];
            radix8_sh(x, stab[63 + L], stab[127 + L], stab[191 + L],
                         stab[255 + L], stab[319 + L], stab[383 + L], stab[447 + L]);
#pragma unroll
            for (int m = 0; m < 8; ++m) buf[fidx(base | (m << 6), c4)] = x[m];
        }
        __syncthreads();

        // ---- iter-1 gather prefetch: issued AFTER the barrier so it is not
        // drained; overlaps all of phase 3 + scatter. ----
        if (it == 0) {
#pragma unroll
            for (int m = 0; m < 8; ++m) {
                uint32_t r3 = __brev((uint32_t)m) >> 29;
                xn[m] = src[((r3 << 8) | r8) * (uint32_t)MSZ + (c0 + 1024u)];
            }
        }

        // ---- phase 3: stages 10-11 (stride 512) + epilogue ----
        uint32_t s256 = 0u, step512 = 0u, tm0 = 0u;
        if (!PASS2) {
            s256    = to_mont(tw[c << 8]);              // Mont(w^(256c))
            step512 = mont_mul(s256, s256);             // Mont(w^(512c))
            tm0     = to_mont(tw[c * (uint32_t)sub]);   // Mont(w^(c*sub)), exp<2^21
        }
#pragma unroll
        for (int gg = 0; gg < 2; ++gg) {
            const int lo = sub + (gg << 8);             // [0,512)
            uint4 y[4];
#pragma unroll
            for (int m = 0; m < 4; ++m) y[m] = buf[fidx(lo | (m << 9), c4)];
            const uint32_t M    = mtab[lo];             // Mont(W^lo)
            const uint32_t t10  = mont_mul(M, M);       // Mont(W^(2lo))
            const uint32_t t111 = mont_mul(M, u1);      // Mont(W^(lo+512))
            bf4_mont(y[0], y[1], t10);  bf4_mont(y[2], y[3], t10);
            bf4_mont(y[0], y[2], M);    bf4_mont(y[1], y[3], t111);

            if (!PASS2) {
                uint32_t tm = tm0;                      // Mont(w^(c*lo))
#pragma unroll
                for (int m = 0; m < 4; ++m) {
                    dst[c * (uint32_t)MSZ + (uint32_t)((m << 9) | lo)] = mm4(tm, y[m]);
                    tm = mont_mul(tm, step512);
                }
                tm0 = mont_mul(tm0, s256);              // advance lo by 256
            } else {
#pragma unroll
                for (int m = 0; m < 4; ++m)
                    dst[(uint32_t)((m << 9) | lo) * (uint32_t)MSZ + c] = mm4(nm, y[m]);
            }
        }
    }
}

// ------------------------------- launch ------------------------------------
extern "C" void kernel_launch(void* const* d_in, const int* in_sizes, int n_in,
                              void* d_out, int out_size, void* d_ws, size_t ws_size,
                              hipStream_t stream)
{
    const uint4*    x    = (const uint4*)d_in[0];      // (N, 4) int32 rows
    const uint32_t* tw   = (const uint32_t*)d_in[1];   // w^k, k < 2^21
    const uint32_t* ninv = (const uint32_t*)d_in[2];
    uint4*          out  = (uint4*)d_out;

    intt_pass<false><<<dim3(512), dim3(512), 0, stream>>>(x, out, tw, ninv);
    intt_pass<true ><<<dim3(512), dim3(512), 0, stream>>>(out, out, tw, ninv);
}

// Round 6
// 202.333 us; speedup vs baseline: 1.0520x; 1.0151x over previous
//
#include <hip/hip_runtime.h>
#include <stdint.h>

// ---------------- modular arithmetic ----------------
static constexpr uint32_t P = 2013265921u;         // 15*2^27 + 1
static constexpr int      LOGM = 11;               // per-block DFT size 2048
static constexpr int      MSZ  = 1 << LOGM;

__host__ __device__ constexpr uint32_t neg_pinv32() {
    uint32_t x = 1u;
    for (int i = 0; i < 5; ++i) x *= 2u - P * x;
    return 0u - x;
}
static constexpr uint32_t NEG_PINV = neg_pinv32();
static constexpr uint32_t R1 = (uint32_t)(((uint64_t)1 << 32) % P);
static constexpr uint32_t R2 = (uint32_t)(((uint64_t)R1 * R1) % P);

// Montgomery (R=2^32). mont_mul(plain, Mont(w)) = plain*w.
__device__ __forceinline__ uint32_t mont_mul(uint32_t a, uint32_t b) {
    uint32_t tlo = a * b;
    uint32_t thi = __umulhi(a, b);
    uint32_t m   = tlo * NEG_PINV;
    uint32_t r   = thi + __umulhi(m, P) + (tlo != 0u);   // r < 2P
    uint32_t s   = r - P;
    return s < r ? s : r;
}
__device__ __forceinline__ uint32_t to_mont(uint32_t a) { return mont_mul(a, R2); }

// Shoup mult by precomputed (w, w'=floor(w*2^32/P)): exact, result [0,P).
__device__ __forceinline__ uint32_t shoup_mul(uint32_t w, uint32_t wp, uint32_t x) {
    uint32_t q = __umulhi(wp, x);
    uint32_t t = w * x - q * P;
    uint32_t s = t - P;
    return s < t ? s : t;
}
__device__ __forceinline__ uint32_t add_p(uint32_t a, uint32_t b) {
    uint32_t r = a + b, s = r - P; return s < r ? s : r;
}
__device__ __forceinline__ uint32_t sub_p(uint32_t a, uint32_t b) {
    uint32_t r = a - b, s = r + P; return s < r ? s : r;
}
__device__ __forceinline__ uint4 mm4(uint32_t w, uint4 v) {
    return make_uint4(mont_mul(w, v.x), mont_mul(w, v.y),
                      mont_mul(w, v.z), mont_mul(w, v.w));
}
__device__ __forceinline__ void bf4_sh(uint4& L, uint4& H, uint2 w) {
    uint4 t = make_uint4(shoup_mul(w.x, w.y, H.x), shoup_mul(w.x, w.y, H.y),
                         shoup_mul(w.x, w.y, H.z), shoup_mul(w.x, w.y, H.w));
    uint4 l = L;
    L = make_uint4(add_p(l.x, t.x), add_p(l.y, t.y), add_p(l.z, t.z), add_p(l.w, t.w));
    H = make_uint4(sub_p(l.x, t.x), sub_p(l.y, t.y), sub_p(l.z, t.z), sub_p(l.w, t.w));
}
__device__ __forceinline__ void bf4_mont(uint4& L, uint4& H, uint32_t wm) {
    uint4 t = mm4(wm, H);
    uint4 l = L;
    L = make_uint4(add_p(l.x, t.x), add_p(l.y, t.y), add_p(l.z, t.z), add_p(l.w, t.w));
    H = make_uint4(sub_p(l.x, t.x), sub_p(l.y, t.y), sub_p(l.z, t.z), sub_p(l.w, t.w));
}
__device__ __forceinline__ void bf4_triv(uint4& L, uint4& H) {
    uint4 l = L, h = H;
    L = make_uint4(add_p(l.x, h.x), add_p(l.y, h.y), add_p(l.z, h.z), add_p(l.w, h.w));
    H = make_uint4(sub_p(l.x, h.x), sub_p(l.y, h.y), sub_p(l.z, h.z), sub_p(l.w, h.w));
}

// LDS element swizzle for the radix-16 phase layout.  Only bits 0-1 of the
// 16B-quad index matter for banking (quad = (2*g+c4)&7); XOR-folding bits
// 4-5 and 8-9 into bits 0-1 makes every phase's 64-lane access set exactly
// 8 lanes/quad (stride-1 A-write, stride-16 B r/w, stride-256 C-read).
// Bijective (modifies low bits from high bits only).
__device__ __forceinline__ int g_sw(int el) {
    return el ^ (((el >> 4) ^ (el >> 8)) & 3);
}
__device__ __forceinline__ int fidx(int el, int c4) { return (g_sw(el) << 1) | c4; }

// One block = 256 threads (4 waves) = one 2048-pt inverse DFT over 2 adjacent
// matrix columns, 16 uint4 elements per thread.  Phases:
//   A: stages 1-4  (radix-16, in registers, quasi-constant twiddles)
//   B: stages 5-8  (radix-16, Shoup twiddles from stab)
//   C: stages 9-11 (2x radix-8, twiddles derived from mtab) + epilogue
// Synchronization: TWO __syncthreads per DFT (round-1 structure had 3 + a
// table barrier).  Barrier 1 covers table publish + A-exchange; barrier 2
// covers B-exchange.  NOTE: a wave-local lgkmcnt-only B->C exchange was
// tried (round 5) and failed the replay race-screen — all cross-thread LDS
// dependencies here use standard barriers only.
// LDS = 64K buf + 2040 stab + 1K mtab ~= 67 KiB -> 2 blocks/CU.
template <bool PASS2>
__global__ __launch_bounds__(256, 2) void intt_pass(
        const uint4* __restrict__ src, uint4* __restrict__ dst,
        const uint32_t* __restrict__ tw,
        const uint32_t* __restrict__ ninv_p)
{
    __shared__ uint4    buf[MSZ * 2];     // 64 KiB
    __shared__ uint2    stab[255];        // stages 5-8: entry e=2^(s-1)-1+j, e in [15,255)
    __shared__ uint32_t mtab[256];        // Mont(W^r), r in [0,256)

    const int      t   = threadIdx.x;
    const int      c4  = t & 1;
    const int      sub = t >> 1;           // [0,128)
    const uint32_t bid = blockIdx.x;
    // XCD swizzle for 1024 blocks: bid&7 = XCD; sibling blocks sharing a 64 B
    // line (grp 2g/2g+1) are 8 bids apart -> same XCD, co-resident.
    const uint32_t grp = ((bid & 7u) << 7) | (bid >> 3);   // [0,1024)
    const uint32_t c   = (grp << 1) | (uint32_t)c4;        // global matrix column

    // table source loads
    uint32_t wv = 0u;
    const bool hasst = (t >= 15) && (t < 255);
    if (hasst) {
        uint32_t ep1 = (uint32_t)t + 1u;
        int sm1 = 31 - __clz((int)ep1);
        uint32_t j = ep1 - (1u << sm1);
        wv = tw[j << (21 - sm1)];          // W^(j*2^(11-s)), s = sm1+1
    }
    uint32_t mv = tw[(uint32_t)t << 11];   // W^t  (W = w^2048)

    // gather: el = 16*sub + i  <-  row rev11(el) = rev4(i)<<7 | rev7(sub)
    const uint32_t r7 = __brev((uint32_t)sub) >> 25;
    uint4 x[16];
#pragma unroll
    for (int i = 0; i < 16; ++i) {
        const uint32_t r4 = __brev((uint32_t)i) >> 28;
        x[i] = src[((r4 << 7) | r7) * (uint32_t)MSZ + c];
    }

    // finish tables (64-bit div + Montgomery convert overlap gather latency)
    if (hasst) {
        uint32_t wp = (uint32_t)((((uint64_t)wv) << 32) / P);
        stab[t] = make_uint2(wv, wp);
    }
    mtab[t] = to_mont(mv);

    // uniform twiddle constants: u1=W^512, u2=W^256, u3=W^768; v4[j]=W^(128j)
    const uint32_t u1 = to_mont(tw[1u << 20]);
    const uint32_t u2 = to_mont(tw[1u << 19]);
    const uint32_t u3 = to_mont(tw[3u << 19]);
    uint32_t v4[8];
    v4[0] = 0u;
#pragma unroll
    for (int j = 1; j < 8; ++j) v4[j] = to_mont(tw[(uint32_t)j << 18]);

    // ---- phase A: stages 1-4 in registers (el = 16*sub + i) ----
    // stage 1: pairs (i, i^1), all trivial
#pragma unroll
    for (int p = 0; p < 8; ++p) bf4_triv(x[2 * p], x[2 * p + 1]);
    // stage 2: pairs (i, i^2), twiddle by i&1: {1, u1}
#pragma unroll
    for (int q = 0; q < 4; ++q) {
        bf4_triv(x[4 * q],     x[4 * q + 2]);
        bf4_mont(x[4 * q + 1], x[4 * q + 3], u1);
    }
    // stage 3: pairs (i, i^4), twiddle by i&3: {1, u2, u1, u3}
#pragma unroll
    for (int h = 0; h < 2; ++h) {
        const int b = 8 * h;
        bf4_triv(x[b],     x[b + 4]);
        bf4_mont(x[b + 1], x[b + 5], u2);
        bf4_mont(x[b + 2], x[b + 6], u1);
        bf4_mont(x[b + 3], x[b + 7], u3);
    }
    // stage 4: pairs (i, i+8), twiddle W^(128*i)
    bf4_triv(x[0], x[8]);
#pragma unroll
    for (int i = 1; i < 8; ++i) bf4_mont(x[i], x[i + 8], v4[i]);

#pragma unroll
    for (int i = 0; i < 16; ++i) buf[fidx(16 * sub + i, c4)] = x[i];

    __syncthreads();   // barrier 1: tables + A-exchange

    // ---- phase B: stages 5-8 (el = k*256 + m*16 + lo4) ----
    const int lo4 = sub >> 3;   // [0,16)
    const int k   = sub & 7;    // [0,8)
#pragma unroll
    for (int m = 0; m < 16; ++m) x[m] = buf[fidx(k * 256 + m * 16 + lo4, c4)];

    const uint2 T5    = stab[15 + lo4];
    const uint2 T6a   = stab[31 + lo4],  T6b = stab[47 + lo4];
    uint2 T7[4];
#pragma unroll
    for (int r = 0; r < 4; ++r) T7[r] = stab[63 + 16 * r + lo4];
    uint2 T8[8];
#pragma unroll
    for (int r = 0; r < 8; ++r) T8[r] = stab[127 + 16 * r + lo4];

    // stage 5: pairs (m, m^1), all twiddle T5 (j = lo4)
#pragma unroll
    for (int p = 0; p < 8; ++p) bf4_sh(x[2 * p], x[2 * p + 1], T5);
    // stage 6: pairs (m, m^2), twiddle by m&1
#pragma unroll
    for (int q = 0; q < 4; ++q) {
        bf4_sh(x[4 * q],     x[4 * q + 2], T6a);
        bf4_sh(x[4 * q + 1], x[4 * q + 3], T6b);
    }
    // stage 7: pairs (m, m^4), twiddle by m&3
#pragma unroll
    for (int h = 0; h < 2; ++h) {
#pragma unroll
        for (int r = 0; r < 4; ++r) bf4_sh(x[8 * h + r], x[8 * h + r + 4], T7[r]);
    }
    // stage 8: pairs (m, m+8), twiddle by m&7
#pragma unroll
    for (int r = 0; r < 8; ++r) bf4_sh(x[r], x[r + 8], T8[r]);

#pragma unroll
    for (int m = 0; m < 16; ++m) buf[fidx(k * 256 + m * 16 + lo4, c4)] = x[m];

    __syncthreads();   // barrier 2: B-exchange

    // ---- phase C: stages 9-11 (el = m*256 + r), two groups r = la, lb ----
    const int la = 32 * k + lo4;           // bit4==0 values of [0,256)
    const int lb = la + 16;                // bit4==1 values
    uint32_t s256 = 0u, nm = 0u;
    if (PASS2) nm = to_mont(*ninv_p);
    else       s256 = to_mont(tw[c << 8]);              // Mont(w^(256c))

#pragma unroll
    for (int g = 0; g < 2; ++g) {
        const int r = g ? lb : la;
        uint4 y[8];
#pragma unroll
        for (int m = 0; m < 8; ++m) y[m] = buf[fidx(m * 256 + r, c4)];

        const uint32_t M    = mtab[r];                  // Mont(W^r)
        const uint32_t M2   = mont_mul(M, M);           // W^(2r)
        const uint32_t t9   = mont_mul(M2, M2);         // W^(4r)   (stage 9)
        const uint32_t t10b = mont_mul(M2, u1);         // W^(2r+512)
        const uint32_t t111 = mont_mul(M, u2);          // W^(r+256)
        const uint32_t t112 = mont_mul(M, u1);          // W^(r+512)
        const uint32_t t113 = mont_mul(M, u3);          // W^(r+768)

        // stage 9: pairs (m, m^1), all t9
        bf4_mont(y[0], y[1], t9); bf4_mont(y[2], y[3], t9);
        bf4_mont(y[4], y[5], t9); bf4_mont(y[6], y[7], t9);
        // stage 10: pairs (m, m^2): m&1 ? t10b : M2
        bf4_mont(y[0], y[2], M2);   bf4_mont(y[1], y[3], t10b);
        bf4_mont(y[4], y[6], M2);   bf4_mont(y[5], y[7], t10b);
        // stage 11: pairs (m, m+4): {M, t111, t112, t113}
        bf4_mont(y[0], y[4], M);    bf4_mont(y[1], y[5], t111);
        bf4_mont(y[2], y[6], t112); bf4_mont(y[3], y[7], t113);

        if (!PASS2) {
            uint32_t tm = to_mont(tw[c * (uint32_t)r]); // Mont(w^(c*r)), < 2^21
#pragma unroll
            for (int m = 0; m < 8; ++m) {
                dst[c * (uint32_t)MSZ + (uint32_t)(m * 256 + r)] = mm4(tm, y[m]);
                tm = mont_mul(tm, s256);
            }
        } else {
#pragma unroll
            for (int m = 0; m < 8; ++m)
                dst[(uint32_t)(m * 256 + r) * (uint32_t)MSZ + c] = mm4(nm, y[m]);
        }
    }
}

// ------------------------------- launch ------------------------------------
extern "C" void kernel_launch(void* const* d_in, const int* in_sizes, int n_in,
                              void* d_out, int out_size, void* d_ws, size_t ws_size,
                              hipStream_t stream)
{
    const uint4*    x    = (const uint4*)d_in[0];      // (N, 4) int32 rows
    const uint32_t* tw   = (const uint32_t*)d_in[1];   // w^k, k < 2^21
    const uint32_t* ninv = (const uint32_t*)d_in[2];
    uint4*          out  = (uint4*)d_out;

    intt_pass<false><<<dim3(1024), dim3(256), 0, stream>>>(x, out, tw, ninv);
    intt_pass<true ><<<dim3(1024), dim3(256), 0, stream>>>(out, out, tw, ninv);
}

// Round 7
// 192.375 us; speedup vs baseline: 1.1065x; 1.0518x over previous
//
#include <hip/hip_runtime.h>
#include <stdint.h>

// ---------------- modular arithmetic ----------------
static constexpr uint32_t P = 2013265921u;         // 15*2^27 + 1
static constexpr int      LOGM = 11;               // per-block DFT size 2048
static constexpr int      MSZ  = 1 << LOGM;
static constexpr int      NCOL = 2;                // matrix columns per block (each el = uint4 = 4 batch cols)

__host__ __device__ constexpr uint32_t neg_pinv32() {
    uint32_t x = 1u;
    for (int i = 0; i < 5; ++i) x *= 2u - P * x;
    return 0u - x;
}
static constexpr uint32_t NEG_PINV = neg_pinv32();
static constexpr uint32_t R1c = (uint32_t)(((uint64_t)1 << 32) % P);
static constexpr uint32_t R2 = (uint32_t)(((uint64_t)R1c * R1c) % P);

// Montgomery (R=2^32). mont_mul(plain, Mont(w)) = plain*w.
__device__ __forceinline__ uint32_t mont_mul(uint32_t a, uint32_t b) {
    uint32_t tlo = a * b;
    uint32_t thi = __umulhi(a, b);
    uint32_t m   = tlo * NEG_PINV;
    uint32_t r   = thi + __umulhi(m, P) + (tlo != 0u);   // r < 2P
    uint32_t s   = r - P;
    return s < r ? s : r;
}
__device__ __forceinline__ uint32_t to_mont(uint32_t a) { return mont_mul(a, R2); }

// Shoup mult by precomputed (w, w'=floor(w*2^32/P)): 4 ops + 2-op reduce.
__device__ __forceinline__ uint32_t shoup_mul(uint32_t w, uint32_t wp, uint32_t x) {
    uint32_t q = __umulhi(wp, x);
    uint32_t t = w * x - q * P;          // exact: t in [0, 2P) < 2^32
    uint32_t s = t - P;
    return s < t ? s : t;
}
__device__ __forceinline__ uint32_t add_p(uint32_t a, uint32_t b) {
    uint32_t r = a + b, s = r - P; return s < r ? s : r;
}
__device__ __forceinline__ uint32_t sub_p(uint32_t a, uint32_t b) {
    uint32_t r = a - b, s = r + P; return s < r ? s : r;
}
__device__ __forceinline__ uint4 mm4(uint32_t w, uint4 v) {   // Montgomery x4
    return make_uint4(mont_mul(w, v.x), mont_mul(w, v.y),
                      mont_mul(w, v.z), mont_mul(w, v.w));
}
// butterfly variants (all keep values canonical [0,P))
__device__ __forceinline__ void bf4_sh(uint4& L, uint4& H, uint2 w) {
    uint4 t = make_uint4(shoup_mul(w.x, w.y, H.x), shoup_mul(w.x, w.y, H.y),
                         shoup_mul(w.x, w.y, H.z), shoup_mul(w.x, w.y, H.w));
    uint4 l = L;
    L = make_uint4(add_p(l.x, t.x), add_p(l.y, t.y), add_p(l.z, t.z), add_p(l.w, t.w));
    H = make_uint4(sub_p(l.x, t.x), sub_p(l.y, t.y), sub_p(l.z, t.z), sub_p(l.w, t.w));
}
__device__ __forceinline__ void bf4_mont(uint4& L, uint4& H, uint32_t wm) {
    uint4 t = mm4(wm, H);
    uint4 l = L;
    L = make_uint4(add_p(l.x, t.x), add_p(l.y, t.y), add_p(l.z, t.z), add_p(l.w, t.w));
    H = make_uint4(sub_p(l.x, t.x), sub_p(l.y, t.y), sub_p(l.z, t.z), sub_p(l.w, t.w));
}
__device__ __forceinline__ void bf4_triv(uint4& L, uint4& H) {   // w == 1
    uint4 l = L, h = H;
    L = make_uint4(add_p(l.x, h.x), add_p(l.y, h.y), add_p(l.z, h.z), add_p(l.w, h.w));
    H = make_uint4(sub_p(l.x, h.x), sub_p(l.y, h.y), sub_p(l.z, h.z), sub_p(l.w, h.w));
}

// LDS element swizzle: conflict-free for strides 1/8/64/512 in the 2-col
// packing (round-1 measured: SQ_LDS_BANK_CONFLICT == 0; round-6's radix-16
// variant measured 639K — this exact g_sw is the proven one).
__device__ __forceinline__ int g_sw(int el) {
    return el ^ (((el >> 3) ^ (el >> 6)) & 7);
}
__device__ __forceinline__ int fidx(int el, int c4) { return (g_sw(el) << 1) | c4; }

// 3 DIT stages (radix-8) with Shoup twiddles (phases 1-2).
__device__ __forceinline__ void radix8_sh(uint4 x[8],
        uint2 ta, uint2 tb0, uint2 tb1,
        uint2 tc0, uint2 tc1, uint2 tc2, uint2 tc3) {
    bf4_sh(x[0], x[1], ta);  bf4_sh(x[2], x[3], ta);
    bf4_sh(x[4], x[5], ta);  bf4_sh(x[6], x[7], ta);
    bf4_sh(x[0], x[2], tb0); bf4_sh(x[1], x[3], tb1);
    bf4_sh(x[4], x[6], tb0); bf4_sh(x[5], x[7], tb1);
    bf4_sh(x[0], x[4], tc0); bf4_sh(x[1], x[5], tc1);
    bf4_sh(x[2], x[6], tc2); bf4_sh(x[3], x[7], tc3);
}

// Round-1 champion structure (62 us/pass: 512 thr, 2 cols, 4 phases,
// 16 waves/CU in 2 barrier domains — measured optimum across rounds 0-6)
// + the two verified micro-wins from rounds 5/6:
//   * stab shrunk 2047 -> 511 entries (stages 4-9 only): build is ~1
//     64-bit div/thread instead of 4 (each div ~40 VALU ops).
//   * phase-3 twiddles derived from mtab[512] (algebra verified twice):
//     W^(2lo) = M*M,  W^lo = M,  W^(lo+512) = M*u1,  M = Mont(W^lo).
// LDS = 64K buf + 4088 stab + 2K mtab = 71672 B -> 2 blocks/CU with
// ~20 KiB headroom (round 1 was an exact 160 KiB fit).
template <bool PASS2>
__global__ __launch_bounds__(512, 4) void intt_pass(
        const uint4* __restrict__ src, uint4* __restrict__ dst,
        const uint32_t* __restrict__ tw,
        const uint32_t* __restrict__ ninv_p)
{
    __shared__ uint4    buf[MSZ * NCOL];  // 64 KiB
    __shared__ uint2    stab[511];        // (w, w_shoup); stage s at 2^(s-1)-1, s=4..9
    __shared__ uint32_t mtab[512];        // Mont(W^lo), lo in [0,512)

    const int      t   = threadIdx.x;
    const int      c4  = t & 1;
    const int      sub = t >> 1;           // [0,256)
    const uint32_t bid = blockIdx.x;
    // XCD swizzle for 1024 blocks (bijective: (bid&7)<<7 | bid>>3): bid&7 =
    // XCD; sibling blocks sharing a 64 B line (grp 2g/2g+1) are 8 bids apart
    // -> same XCD, co-resident -> L2 line merge on the 32 B gather granules.
    const uint32_t grp = ((bid & 7u) << 7) | (bid >> 3);   // [0,1024)
    const uint32_t c   = (grp << 1) | (uint32_t)c4;        // global matrix column

    // table source loads (1 stab entry for t<511, 1 mtab entry per thread)
    uint32_t wv = 0u;
    if (t < 511) {
        uint32_t ep1 = (uint32_t)t + 1u;
        int sm1 = 31 - __clz((int)ep1);
        uint32_t j = ep1 - (1u << sm1);
        wv = tw[j << (21 - sm1)];          // W^(j*2^(11-s)), s = sm1+1, W = w^2048
    }
    uint32_t mv = tw[(uint32_t)t << 11];   // W^t

    // global gather, bit-reversal folded in: el = 8*sub+m <- row rev11(el)
    const uint32_t r8 = __brev((uint32_t)sub) >> 24;
    uint4 x[8];
#pragma unroll
    for (int m = 0; m < 8; ++m) {
        uint32_t r3 = __brev((uint32_t)m) >> 29;
        x[m] = src[((r3 << 8) | r8) * (uint32_t)MSZ + c];
    }

    // finish tables (64-bit div + Montgomery convert overlap gather latency)
    if (t < 511) {
        uint32_t wp = (uint32_t)((((uint64_t)wv) << 32) / P);
        stab[t] = make_uint2(wv, wp);
    }
    mtab[t] = to_mont(mv);

    // phase-0 non-trivial twiddles (uniform): u1=W^512, u2=W^256, u3=W^768
    const uint32_t u1 = to_mont(tw[1u << 20]);
    const uint32_t u2 = to_mont(tw[1u << 19]);
    const uint32_t u3 = to_mont(tw[3u << 19]);

    // ---- phase 0: stages 1-3, j=0 group (7 of 12 butterflies are w=1) ----
    bf4_triv(x[0], x[1]);  bf4_triv(x[2], x[3]);
    bf4_triv(x[4], x[5]);  bf4_triv(x[6], x[7]);
    bf4_triv(x[0], x[2]);  bf4_mont(x[1], x[3], u1);
    bf4_triv(x[4], x[6]);  bf4_mont(x[5], x[7], u1);
    bf4_triv(x[0], x[4]);  bf4_mont(x[1], x[5], u2);
    bf4_mont(x[2], x[6], u1); bf4_mont(x[3], x[7], u3);
#pragma unroll
    for (int m = 0; m < 8; ++m) buf[fidx(8 * sub + m, c4)] = x[m];
    __syncthreads();   // covers tables AND phase-0 buf

    // ---- phase 1: stages 4-6 (element stride 8) ----
    {
        const int L = sub & 7, hi = sub >> 3;
        const int base = (hi << 6) | L;
#pragma unroll
        for (int m = 0; m < 8; ++m) x[m] = buf[fidx(base | (m << 3), c4)];
        radix8_sh(x, stab[7 + L], stab[15 + L], stab[23 + L],
                     stab[31 + L], stab[39 + L], stab[47 + L], stab[55 + L]);
#pragma unroll
        for (int m = 0; m < 8; ++m) buf[fidx(base | (m << 3), c4)] = x[m];
    }
    __syncthreads();

    // ---- phase 2: stages 7-9 (element stride 64) ----
    {
        const int L = sub & 63, hi = sub >> 6;
        const int base = (hi << 9) | L;
#pragma unroll
        for (int m = 0; m < 8; ++m) x[m] = buf[fidx(base | (m << 6), c4)];
        radix8_sh(x, stab[63 + L], stab[127 + L], stab[191 + L],
                     stab[255 + L], stab[319 + L], stab[383 + L], stab[447 + L]);
#pragma unroll
        for (int m = 0; m < 8; ++m) buf[fidx(base | (m << 6), c4)] = x[m];
    }
    __syncthreads();

    // ---- phase 3: stages 10-11 (stride 512) + epilogue ----
    // Twiddles from mtab: stage 10 uses W^(2lo) = M*M; stage 11 uses W^lo = M
    // and W^(lo+512) = M * u1.
    uint32_t nm = 0u, s256 = 0u, step512 = 0u, tm0 = 0u;
    if (PASS2) {
        nm = to_mont(*ninv_p);
    } else {
        s256    = to_mont(tw[c << 8]);              // Mont(w^(256c))
        step512 = mont_mul(s256, s256);             // Mont(w^(512c))
        tm0     = to_mont(tw[c * (uint32_t)sub]);   // Mont(w^(c*sub)), exp<2^19
    }
#pragma unroll
    for (int gg = 0; gg < 2; ++gg) {
        const int lo = sub + (gg << 8);             // [0,512)
        uint4 y[4];
#pragma unroll
        for (int m = 0; m < 4; ++m) y[m] = buf[fidx(lo | (m << 9), c4)];
        const uint32_t M    = mtab[lo];             // Mont(W^lo)
        const uint32_t t10  = mont_mul(M, M);       // Mont(W^(2lo))
        const uint32_t t111 = mont_mul(M, u1);      // Mont(W^(lo+512))
        bf4_mont(y[0], y[1], t10);  bf4_mont(y[2], y[3], t10);
        bf4_mont(y[0], y[2], M);    bf4_mont(y[1], y[3], t111);

        if (!PASS2) {
            uint32_t tm = tm0;                      // Mont(w^(c*lo))
#pragma unroll
            for (int m = 0; m < 4; ++m) {
                dst[c * (uint32_t)MSZ + (uint32_t)((m << 9) | lo)] = mm4(tm, y[m]);
                tm = mont_mul(tm, step512);
            }
            tm0 = mont_mul(tm0, s256);              // advance lo by 256
        } else {
#pragma unroll
            for (int m = 0; m < 4; ++m)
                dst[(uint32_t)((m << 9) | lo) * (uint32_t)MSZ + c] = mm4(nm, y[m]);
        }
    }
}

// ------------------------------- launch ------------------------------------
extern "C" void kernel_launch(void* const* d_in, const int* in_sizes, int n_in,
                              void* d_out, int out_size, void* d_ws, size_t ws_size,
                              hipStream_t stream)
{
    const uint4*    x    = (const uint4*)d_in[0];      // (N, 4) int32 rows
    const uint32_t* tw   = (const uint32_t*)d_in[1];   // w^k, k < 2^21
    const uint32_t* ninv = (const uint32_t*)d_in[2];
    uint4*          out  = (uint4*)d_out;

    intt_pass<false><<<dim3(1024), dim3(512), 0, stream>>>(x, out, tw, ninv);
    intt_pass<true ><<<dim3(1024), dim3(512), 0, stream>>>(out, out, tw, ninv);
}

// Round 8
// 190.707 us; speedup vs baseline: 1.1161x; 1.0087x over previous
//
#include <hip/hip_runtime.h>
#include <stdint.h>

// ---------------- modular arithmetic ----------------
static constexpr uint32_t P = 2013265921u;         // 15*2^27 + 1
static constexpr int      LOGM = 11;               // per-block DFT size 2048
static constexpr int      MSZ  = 1 << LOGM;
static constexpr int      NCOL = 2;                // matrix columns per block (each el = uint4 = 4 batch cols)

__host__ __device__ constexpr uint32_t neg_pinv32() {
    uint32_t x = 1u;
    for (int i = 0; i < 5; ++i) x *= 2u - P * x;
    return 0u - x;
}
static constexpr uint32_t NEG_PINV = neg_pinv32();
static constexpr uint32_t R1c = (uint32_t)(((uint64_t)1 << 32) % P);
static constexpr uint32_t R2 = (uint32_t)(((uint64_t)R1c * R1c) % P);

// Montgomery (R=2^32). mont_mul(plain, Mont(w)) = plain*w.
__device__ __forceinline__ uint32_t mont_mul(uint32_t a, uint32_t b) {
    uint32_t tlo = a * b;
    uint32_t thi = __umulhi(a, b);
    uint32_t m   = tlo * NEG_PINV;
    uint32_t r   = thi + __umulhi(m, P) + (tlo != 0u);   // r < 2P
    uint32_t s   = r - P;
    return s < r ? s : r;
}
__device__ __forceinline__ uint32_t to_mont(uint32_t a) { return mont_mul(a, R2); }

// Shoup mult by precomputed (w, w'=floor(w*2^32/P)): 4 ops + 2-op reduce.
__device__ __forceinline__ uint32_t shoup_mul(uint32_t w, uint32_t wp, uint32_t x) {
    uint32_t q = __umulhi(wp, x);
    uint32_t t = w * x - q * P;          // exact: t in [0, 2P) < 2^32
    uint32_t s = t - P;
    return s < t ? s : t;
}
__device__ __forceinline__ uint32_t add_p(uint32_t a, uint32_t b) {
    uint32_t r = a + b, s = r - P; return s < r ? s : r;
}
__device__ __forceinline__ uint32_t sub_p(uint32_t a, uint32_t b) {
    uint32_t r = a - b, s = r + P; return s < r ? s : r;
}
__device__ __forceinline__ uint4 mm4(uint32_t w, uint4 v) {   // Montgomery x4
    return make_uint4(mont_mul(w, v.x), mont_mul(w, v.y),
                      mont_mul(w, v.z), mont_mul(w, v.w));
}
// butterfly variants (all keep values canonical [0,P))
__device__ __forceinline__ void bf4_sh(uint4& L, uint4& H, uint2 w) {
    uint4 t = make_uint4(shoup_mul(w.x, w.y, H.x), shoup_mul(w.x, w.y, H.y),
                         shoup_mul(w.x, w.y, H.z), shoup_mul(w.x, w.y, H.w));
    uint4 l = L;
    L = make_uint4(add_p(l.x, t.x), add_p(l.y, t.y), add_p(l.z, t.z), add_p(l.w, t.w));
    H = make_uint4(sub_p(l.x, t.x), sub_p(l.y, t.y), sub_p(l.z, t.z), sub_p(l.w, t.w));
}
__device__ __forceinline__ void bf4_mont(uint4& L, uint4& H, uint32_t wm) {
    uint4 t = mm4(wm, H);
    uint4 l = L;
    L = make_uint4(add_p(l.x, t.x), add_p(l.y, t.y), add_p(l.z, t.z), add_p(l.w, t.w));
    H = make_uint4(sub_p(l.x, t.x), sub_p(l.y, t.y), sub_p(l.z, t.z), sub_p(l.w, t.w));
}
__device__ __forceinline__ void bf4_triv(uint4& L, uint4& H) {   // w == 1
    uint4 l = L, h = H;
    L = make_uint4(add_p(l.x, h.x), add_p(l.y, h.y), add_p(l.z, h.z), add_p(l.w, h.w));
    H = make_uint4(sub_p(l.x, h.x), sub_p(l.y, h.y), sub_p(l.z, h.z), sub_p(l.w, h.w));
}

// LDS element swizzle: conflict-free for strides 1/8/64/512 in the 2-col
// packing (round-1 measured: SQ_LDS_BANK_CONFLICT == 0).
__device__ __forceinline__ int g_sw(int el) {
    return el ^ (((el >> 3) ^ (el >> 6)) & 7);
}
__device__ __forceinline__ int fidx(int el, int c4) { return (g_sw(el) << 1) | c4; }

// 3 DIT stages (radix-8) with Shoup twiddles (phases 1-2).
__device__ __forceinline__ void radix8_sh(uint4 x[8],
        uint2 ta, uint2 tb0, uint2 tb1,
        uint2 tc0, uint2 tc1, uint2 tc2, uint2 tc3) {
    bf4_sh(x[0], x[1], ta);  bf4_sh(x[2], x[3], ta);
    bf4_sh(x[4], x[5], ta);  bf4_sh(x[6], x[7], ta);
    bf4_sh(x[0], x[2], tb0); bf4_sh(x[1], x[3], tb1);
    bf4_sh(x[4], x[6], tb0); bf4_sh(x[5], x[7], tb1);
    bf4_sh(x[0], x[4], tc0); bf4_sh(x[1], x[5], tc1);
    bf4_sh(x[2], x[6], tc2); bf4_sh(x[3], x[7], tc3);
}

// Round-7 champion structure (60.2 us/pass) + latency-pocket drains:
//   * PASS1 epilogue twiddles (tw[c<<8], tw[c*sub]) + all 8 tm values are
//     loaded/derived at kernel start, overlapping the gather latency —
//     removes a global-load + serial mont chain from the block tail.
//   * Phase-2's 7 stab twiddles and phase-3's mtab entries (+derived
//     constants) are prefetched into registers during phase 1.  stab/mtab
//     are IMMUTABLE after barrier 1, so carrying these regs across
//     barriers 2/3 has no hazard (no sync-structure change; R5 lesson).
// LDS = 64K buf + 4088 stab + 2K mtab = 71672 B -> 2 blocks/CU.
template <bool PASS2>
__global__ __launch_bounds__(512, 4) void intt_pass(
        const uint4* __restrict__ src, uint4* __restrict__ dst,
        const uint32_t* __restrict__ tw,
        const uint32_t* __restrict__ ninv_p)
{
    __shared__ uint4    buf[MSZ * NCOL];  // 64 KiB
    __shared__ uint2    stab[511];        // (w, w_shoup); stage s at 2^(s-1)-1, s=4..9
    __shared__ uint32_t mtab[512];        // Mont(W^lo), lo in [0,512)

    const int      t   = threadIdx.x;
    const int      c4  = t & 1;
    const int      sub = t >> 1;           // [0,256)
    const uint32_t bid = blockIdx.x;
    // XCD swizzle for 1024 blocks: bid&7 = XCD; sibling blocks sharing a 64 B
    // line (grp 2g/2g+1) are 8 bids apart -> same XCD, co-resident.
    const uint32_t grp = ((bid & 7u) << 7) | (bid >> 3);   // [0,1024)
    const uint32_t c   = (grp << 1) | (uint32_t)c4;        // global matrix column

    // table source loads (1 stab entry for t<511, 1 mtab entry per thread)
    uint32_t wv = 0u;
    if (t < 511) {
        uint32_t ep1 = (uint32_t)t + 1u;
        int sm1 = 31 - __clz((int)ep1);
        uint32_t j = ep1 - (1u << sm1);
        wv = tw[j << (21 - sm1)];          // W^(j*2^(11-s)), s = sm1+1, W = w^2048
    }
    uint32_t mv = tw[(uint32_t)t << 11];   // W^t

    // PASS1 epilogue source loads — issue before the gather so the 64-bit
    // div + mont chain below overlaps their latency too.
    uint32_t e256 = 0u, esub = 0u;
    if (!PASS2) {
        e256 = tw[c << 8];                 // w^(256c)
        esub = tw[c * (uint32_t)sub];      // w^(c*sub), exp < 2^19
    }

    // global gather, bit-reversal folded in: el = 8*sub+m <- row rev11(el)
    const uint32_t r8 = __brev((uint32_t)sub) >> 24;
    uint4 x[8];
#pragma unroll
    for (int m = 0; m < 8; ++m) {
        uint32_t r3 = __brev((uint32_t)m) >> 29;
        x[m] = src[((r3 << 8) | r8) * (uint32_t)MSZ + c];
    }

    // finish tables (64-bit div + Montgomery convert overlap gather latency)
    if (t < 511) {
        uint32_t wp = (uint32_t)((((uint64_t)wv) << 32) / P);
        stab[t] = make_uint2(wv, wp);
    }
    mtab[t] = to_mont(mv);

    // phase-0 non-trivial twiddles (uniform): u1=W^512, u2=W^256, u3=W^768
    const uint32_t u1 = to_mont(tw[1u << 20]);
    const uint32_t u2 = to_mont(tw[1u << 19]);
    const uint32_t u3 = to_mont(tw[3u << 19]);

    // PASS1 epilogue precompute (gather window): tmv[gg*4+m] =
    // Mont(w^(c*(lo))) for lo = sub + gg*256 + m*512.
    uint32_t nm = 0u, tmv[8];
    if (PASS2) {
        nm = to_mont(*ninv_p);
    } else {
        uint32_t s256    = to_mont(e256);             // Mont(w^(256c))
        uint32_t step512 = mont_mul(s256, s256);      // Mont(w^(512c))
        tmv[0] = to_mont(esub);                       // Mont(w^(c*sub))
        tmv[1] = mont_mul(tmv[0], step512);
        tmv[2] = mont_mul(tmv[1], step512);
        tmv[3] = mont_mul(tmv[2], step512);
        tmv[4] = mont_mul(tmv[0], s256);
        tmv[5] = mont_mul(tmv[4], step512);
        tmv[6] = mont_mul(tmv[5], step512);
        tmv[7] = mont_mul(tmv[6], step512);
    }

    // ---- phase 0: stages 1-3, j=0 group (7 of 12 butterflies are w=1) ----
    bf4_triv(x[0], x[1]);  bf4_triv(x[2], x[3]);
    bf4_triv(x[4], x[5]);  bf4_triv(x[6], x[7]);
    bf4_triv(x[0], x[2]);  bf4_mont(x[1], x[3], u1);
    bf4_triv(x[4], x[6]);  bf4_mont(x[5], x[7], u1);
    bf4_triv(x[0], x[4]);  bf4_mont(x[1], x[5], u2);
    bf4_mont(x[2], x[6], u1); bf4_mont(x[3], x[7], u3);
#pragma unroll
    for (int m = 0; m < 8; ++m) buf[fidx(8 * sub + m, c4)] = x[m];
    __syncthreads();   // barrier 1: tables + phase-0 buf

    // Prefetch registers for phases 2 and 3 — stab/mtab are constant after
    // barrier 1, so these survive barriers 2/3 untouched.
    uint2 p2t[7];
    uint32_t Ma, Mb, t10a, t10b, t111a, t111b;

    // ---- phase 1: stages 4-6 (element stride 8) ----
    {
        const int L = sub & 7, hi = sub >> 3;
        const int base = (hi << 6) | L;
#pragma unroll
        for (int m = 0; m < 8; ++m) x[m] = buf[fidx(base | (m << 3), c4)];

        // phase-2/3 twiddle prefetch (overlaps phase-1 compute)
        const int L2 = sub & 63;
#pragma unroll
        for (int r = 0; r < 7; ++r) p2t[r] = stab[63 + (r << 6) + L2];
        Ma = mtab[sub];            Mb = mtab[sub + 256];
        t10a  = mont_mul(Ma, Ma);  t10b  = mont_mul(Mb, Mb);
        t111a = mont_mul(Ma, u1);  t111b = mont_mul(Mb, u1);

        radix8_sh(x, stab[7 + L], stab[15 + L], stab[23 + L],
                     stab[31 + L], stab[39 + L], stab[47 + L], stab[55 + L]);
#pragma unroll
        for (int m = 0; m < 8; ++m) buf[fidx(base | (m << 3), c4)] = x[m];
    }
    __syncthreads();

    // ---- phase 2: stages 7-9 (element stride 64), twiddles prefetched ----
    {
        const int L = sub & 63, hi = sub >> 6;
        const int base = (hi << 9) | L;
#pragma unroll
        for (int m = 0; m < 8; ++m) x[m] = buf[fidx(base | (m << 6), c4)];
        radix8_sh(x, p2t[0], p2t[1], p2t[2], p2t[3], p2t[4], p2t[5], p2t[6]);
#pragma unroll
        for (int m = 0; m < 8; ++m) buf[fidx(base | (m << 6), c4)] = x[m];
    }
    __syncthreads();

    // ---- phase 3: stages 10-11 (stride 512) + epilogue, all constants
    // already in registers ----
#pragma unroll
    for (int gg = 0; gg < 2; ++gg) {
        const int lo = sub + (gg << 8);             // [0,512)
        uint4 y[4];
#pragma unroll
        for (int m = 0; m < 4; ++m) y[m] = buf[fidx(lo | (m << 9), c4)];
        const uint32_t M    = gg ? Mb    : Ma;      // Mont(W^lo)
        const uint32_t t10  = gg ? t10b  : t10a;    // Mont(W^(2lo))
        const uint32_t t111 = gg ? t111b : t111a;   // Mont(W^(lo+512))
        bf4_mont(y[0], y[1], t10);  bf4_mont(y[2], y[3], t10);
        bf4_mont(y[0], y[2], M);    bf4_mont(y[1], y[3], t111);

        if (!PASS2) {
#pragma unroll
            for (int m = 0; m < 4; ++m)
                dst[c * (uint32_t)MSZ + (uint32_t)((m << 9) | lo)] =
                    mm4(tmv[(gg << 2) | m], y[m]);
        } else {
#pragma unroll
            for (int m = 0; m < 4; ++m)
                dst[(uint32_t)((m << 9) | lo) * (uint32_t)MSZ + c] = mm4(nm, y[m]);
        }
    }
}

// ------------------------------- launch ------------------------------------
extern "C" void kernel_launch(void* const* d_in, const int* in_sizes, int n_in,
                              void* d_out, int out_size, void* d_ws, size_t ws_size,
                              hipStream_t stream)
{
    const uint4*    x    = (const uint4*)d_in[0];      // (N, 4) int32 rows
    const uint32_t* tw   = (const uint32_t*)d_in[1];   // w^k, k < 2^21
    const uint32_t* ninv = (const uint32_t*)d_in[2];
    uint4*          out  = (uint4*)d_out;

    intt_pass<false><<<dim3(1024), dim3(512), 0, stream>>>(x, out, tw, ninv);
    intt_pass<true ><<<dim3(1024), dim3(512), 0, stream>>>(out, out, tw, ninv);
}

// Round 9
// 189.129 us; speedup vs baseline: 1.1255x; 1.0083x over previous
//
#include <hip/hip_runtime.h>
#include <stdint.h>

// ---------------- modular arithmetic ----------------
static constexpr uint32_t P = 2013265921u;         // 15*2^27 + 1
static constexpr int      LOGM = 11;               // per-block DFT size 2048
static constexpr int      MSZ  = 1 << LOGM;

__host__ __device__ constexpr uint32_t neg_pinv32() {
    uint32_t x = 1u;
    for (int i = 0; i < 5; ++i) x *= 2u - P * x;
    return 0u - x;
}
static constexpr uint32_t NEG_PINV = neg_pinv32();
static constexpr uint32_t R1c = (uint32_t)(((uint64_t)1 << 32) % P);
static constexpr uint32_t R2 = (uint32_t)(((uint64_t)R1c * R1c) % P);

// Montgomery (R=2^32). mont_mul(plain, Mont(w)) = plain*w.
__device__ __forceinline__ uint32_t mont_mul(uint32_t a, uint32_t b) {
    uint32_t tlo = a * b;
    uint32_t thi = __umulhi(a, b);
    uint32_t m   = tlo * NEG_PINV;
    uint32_t r   = thi + __umulhi(m, P) + (tlo != 0u);   // r < 2P
    uint32_t s   = r - P;
    return s < r ? s : r;
}
__device__ __forceinline__ uint32_t to_mont(uint32_t a) { return mont_mul(a, R2); }

// Shoup mult by precomputed (w, w'=floor(w*2^32/P)): 4 ops + 2-op reduce.
__device__ __forceinline__ uint32_t shoup_mul(uint32_t w, uint32_t wp, uint32_t x) {
    uint32_t q = __umulhi(wp, x);
    uint32_t t = w * x - q * P;          // exact: t in [0, 2P) < 2^32
    uint32_t s = t - P;
    return s < t ? s : t;
}
__device__ __forceinline__ uint32_t add_p(uint32_t a, uint32_t b) {
    uint32_t r = a + b, s = r - P; return s < r ? s : r;
}
__device__ __forceinline__ uint32_t sub_p(uint32_t a, uint32_t b) {
    uint32_t r = a - b, s = r + P; return s < r ? s : r;
}
__device__ __forceinline__ uint4 mm4(uint32_t w, uint4 v) {   // Montgomery x4
    return make_uint4(mont_mul(w, v.x), mont_mul(w, v.y),
                      mont_mul(w, v.z), mont_mul(w, v.w));
}
// butterfly variants (all keep values canonical [0,P))
__device__ __forceinline__ void bf4_sh(uint4& L, uint4& H, uint2 w) {
    uint4 t = make_uint4(shoup_mul(w.x, w.y, H.x), shoup_mul(w.x, w.y, H.y),
                         shoup_mul(w.x, w.y, H.z), shoup_mul(w.x, w.y, H.w));
    uint4 l = L;
    L = make_uint4(add_p(l.x, t.x), add_p(l.y, t.y), add_p(l.z, t.z), add_p(l.w, t.w));
    H = make_uint4(sub_p(l.x, t.x), sub_p(l.y, t.y), sub_p(l.z, t.z), sub_p(l.w, t.w));
}
__device__ __forceinline__ void bf4_mont(uint4& L, uint4& H, uint32_t wm) {
    uint4 t = mm4(wm, H);
    uint4 l = L;
    L = make_uint4(add_p(l.x, t.x), add_p(l.y, t.y), add_p(l.z, t.z), add_p(l.w, t.w));
    H = make_uint4(sub_p(l.x, t.x), sub_p(l.y, t.y), sub_p(l.z, t.z), sub_p(l.w, t.w));
}
__device__ __forceinline__ void bf4_triv(uint4& L, uint4& H) {   // w == 1
    uint4 l = L, h = H;
    L = make_uint4(add_p(l.x, h.x), add_p(l.y, h.y), add_p(l.z, h.z), add_p(l.w, h.w));
    H = make_uint4(sub_p(l.x, h.x), sub_p(l.y, h.y), sub_p(l.z, h.z), sub_p(l.w, h.w));
}

// 3 DIT stages (radix-8) with Shoup twiddles (phases 1-2).
__device__ __forceinline__ void radix8_sh(uint4 x[8],
        uint2 ta, uint2 tb0, uint2 tb1,
        uint2 tc0, uint2 tc1, uint2 tc2, uint2 tc3) {
    bf4_sh(x[0], x[1], ta);  bf4_sh(x[2], x[3], ta);
    bf4_sh(x[4], x[5], ta);  bf4_sh(x[6], x[7], ta);
    bf4_sh(x[0], x[2], tb0); bf4_sh(x[1], x[3], tb1);
    bf4_sh(x[4], x[6], tb0); bf4_sh(x[5], x[7], tb1);
    bf4_sh(x[0], x[4], tc0); bf4_sh(x[1], x[5], tc1);
    bf4_sh(x[2], x[6], tc2); bf4_sh(x[3], x[7], tc3);
}

// R7/R8 champion structure (60 us/pass) with PADDED LDS layout replacing the
// XOR swizzle: phys = el + (el>>3)  (pad 1 per 8 elements, injective since
// f is strictly increasing).  Two verified-by-derivation properties:
//   * conflict-free: bank-quad q = (2*phys + c4)&7 is exactly 8 lanes/quad
//     for every phase's 64-lane access set (phase 0/1: q=(2L+2m+c4)&7 with
//     L uniform over [0,8); phase 2/3: m-terms are 0 mod 8 and
//     q=(2(L+(L>>3))+c4)&7, uniform over any 32 consecutive subs) — the
//     same distribution the measured-0-conflict XOR swizzle produced.
//   * constant per-phase strides: 9m / 72m / 576m elements (288/2304/18432
//     bytes) -> ONE base-address calc per phase + ds offset: immediates,
//     deleting ~48 data-dependent fidx() computations (~200 VALU ops) per
//     thread per pass.  That tax was ~1/3 of non-butterfly VALU issue.
// LDS = 73728 buf + 4088 stab + 2048 mtab = 79864 B -> 2 blocks/CU.
template <bool PASS2>
__global__ __launch_bounds__(512, 4) void intt_pass(
        const uint4* __restrict__ src, uint4* __restrict__ dst,
        const uint32_t* __restrict__ tw,
        const uint32_t* __restrict__ ninv_p)
{
    __shared__ uint4    buf[2304 * 2];    // 72 KiB padded (max phys = 2302)
    __shared__ uint2    stab[511];        // (w, w_shoup); stage s at 2^(s-1)-1, s=4..9
    __shared__ uint32_t mtab[512];        // Mont(W^lo), lo in [0,512)

    const int      t   = threadIdx.x;
    const int      c4  = t & 1;
    const int      sub = t >> 1;           // [0,256)
    const uint32_t bid = blockIdx.x;
    // XCD swizzle for 1024 blocks: bid&7 = XCD; sibling blocks sharing a 64 B
    // line (grp 2g/2g+1) are 8 bids apart -> same XCD, co-resident.
    const uint32_t grp = ((bid & 7u) << 7) | (bid >> 3);   // [0,1024)
    const uint32_t c   = (grp << 1) | (uint32_t)c4;        // global matrix column

    // table source loads (1 stab entry for t<511, 1 mtab entry per thread)
    uint32_t wv = 0u;
    if (t < 511) {
        uint32_t ep1 = (uint32_t)t + 1u;
        int sm1 = 31 - __clz((int)ep1);
        uint32_t j = ep1 - (1u << sm1);
        wv = tw[j << (21 - sm1)];          // W^(j*2^(11-s)), s = sm1+1, W = w^2048
    }
    uint32_t mv = tw[(uint32_t)t << 11];   // W^t

    // PASS1 epilogue source loads — issued before the gather.
    uint32_t e256 = 0u, esub = 0u;
    if (!PASS2) {
        e256 = tw[c << 8];                 // w^(256c)
        esub = tw[c * (uint32_t)sub];      // w^(c*sub), exp < 2^19
    }

    // global gather, bit-reversal folded in: el = 8*sub+m <- row rev11(el)
    const uint32_t r8 = __brev((uint32_t)sub) >> 24;
    uint4 x[8];
#pragma unroll
    for (int m = 0; m < 8; ++m) {
        uint32_t r3 = __brev((uint32_t)m) >> 29;
        x[m] = src[((r3 << 8) | r8) * (uint32_t)MSZ + c];
    }

    // finish tables (64-bit div + Montgomery convert overlap gather latency)
    if (t < 511) {
        uint32_t wp = (uint32_t)((((uint64_t)wv) << 32) / P);
        stab[t] = make_uint2(wv, wp);
    }
    mtab[t] = to_mont(mv);

    // phase-0 non-trivial twiddles (uniform): u1=W^512, u2=W^256, u3=W^768
    const uint32_t u1 = to_mont(tw[1u << 20]);
    const uint32_t u2 = to_mont(tw[1u << 19]);
    const uint32_t u3 = to_mont(tw[3u << 19]);

    // PASS1 epilogue precompute (gather window)
    uint32_t nm = 0u, tmv[8];
    if (PASS2) {
        nm = to_mont(*ninv_p);
    } else {
        uint32_t s256    = to_mont(e256);             // Mont(w^(256c))
        uint32_t step512 = mont_mul(s256, s256);      // Mont(w^(512c))
        tmv[0] = to_mont(esub);                       // Mont(w^(c*sub))
        tmv[1] = mont_mul(tmv[0], step512);
        tmv[2] = mont_mul(tmv[1], step512);
        tmv[3] = mont_mul(tmv[2], step512);
        tmv[4] = mont_mul(tmv[0], s256);
        tmv[5] = mont_mul(tmv[4], step512);
        tmv[6] = mont_mul(tmv[5], step512);
        tmv[7] = mont_mul(tmv[6], step512);
    }

    // ---- phase 0: stages 1-3, j=0 group (7 of 12 butterflies are w=1) ----
    bf4_triv(x[0], x[1]);  bf4_triv(x[2], x[3]);
    bf4_triv(x[4], x[5]);  bf4_triv(x[6], x[7]);
    bf4_triv(x[0], x[2]);  bf4_mont(x[1], x[3], u1);
    bf4_triv(x[4], x[6]);  bf4_mont(x[5], x[7], u1);
    bf4_triv(x[0], x[4]);  bf4_mont(x[1], x[5], u2);
    bf4_mont(x[2], x[6], u1); bf4_mont(x[3], x[7], u3);
    {   // phys(8*sub+m) = 9*sub + m  -> stride 2 uint4 (32 B immediates)
        uint4* bp = &buf[((9 * sub) << 1) | c4];
#pragma unroll
        for (int m = 0; m < 8; ++m) bp[2 * m] = x[m];
    }
    __syncthreads();   // barrier 1: tables + phase-0 buf

    uint2 p2t[7];
    uint32_t Ma, Mb, t10a, t10b, t111a, t111b;

    // ---- phase 1: stages 4-6 (element stride 8) ----
    {
        const int L = sub & 7, hi = sub >> 3;
        // phys(base | m<<3) = 72*hi + L + 9*m  -> stride 18 uint4 (288 B)
        uint4* bp = &buf[((72 * hi + L) << 1) | c4];
#pragma unroll
        for (int m = 0; m < 8; ++m) x[m] = bp[18 * m];

        // phase-2/3 twiddle prefetch (overlaps phase-1 compute)
        const int L2 = sub & 63;
#pragma unroll
        for (int r = 0; r < 7; ++r) p2t[r] = stab[63 + (r << 6) + L2];
        Ma = mtab[sub];            Mb = mtab[sub + 256];
        t10a  = mont_mul(Ma, Ma);  t10b  = mont_mul(Mb, Mb);
        t111a = mont_mul(Ma, u1);  t111b = mont_mul(Mb, u1);

        radix8_sh(x, stab[7 + L], stab[15 + L], stab[23 + L],
                     stab[31 + L], stab[39 + L], stab[47 + L], stab[55 + L]);
#pragma unroll
        for (int m = 0; m < 8; ++m) bp[18 * m] = x[m];
    }
    __syncthreads();

    // ---- phase 2: stages 7-9 (element stride 64), twiddles prefetched ----
    {
        const int L = sub & 63, hi = sub >> 6;
        // phys(base | m<<6) = 576*hi + L + (L>>3) + 72*m -> stride 144 uint4
        uint4* bp = &buf[((576 * hi + L + (L >> 3)) << 1) | c4];
#pragma unroll
        for (int m = 0; m < 8; ++m) x[m] = bp[144 * m];
        radix8_sh(x, p2t[0], p2t[1], p2t[2], p2t[3], p2t[4], p2t[5], p2t[6]);
#pragma unroll
        for (int m = 0; m < 8; ++m) bp[144 * m] = x[m];
    }
    __syncthreads();

    // ---- phase 3: stages 10-11 (stride 512) + epilogue ----
#pragma unroll
    for (int gg = 0; gg < 2; ++gg) {
        const int lo = sub + (gg << 8);             // [0,512)
        // phys(lo + m*512) = lo + (lo>>3) + 576*m  -> stride 1152 uint4
        uint4* bp = &buf[((lo + (lo >> 3)) << 1) | c4];
        uint4 y[4];
#pragma unroll
        for (int m = 0; m < 4; ++m) y[m] = bp[1152 * m];
        const uint32_t M    = gg ? Mb    : Ma;      // Mont(W^lo)
        const uint32_t t10  = gg ? t10b  : t10a;    // Mont(W^(2lo))
        const uint32_t t111 = gg ? t111b : t111a;   // Mont(W^(lo+512))
        bf4_mont(y[0], y[1], t10);  bf4_mont(y[2], y[3], t10);
        bf4_mont(y[0], y[2], M);    bf4_mont(y[1], y[3], t111);

        if (!PASS2) {
#pragma unroll
            for (int m = 0; m < 4; ++m)
                dst[c * (uint32_t)MSZ + (uint32_t)((m << 9) | lo)] =
                    mm4(tmv[(gg << 2) | m], y[m]);
        } else {
#pragma unroll
            for (int m = 0; m < 4; ++m)
                dst[(uint32_t)((m << 9) | lo) * (uint32_t)MSZ + c] = mm4(nm, y[m]);
        }
    }
}

// ------------------------------- launch ------------------------------------
extern "C" void kernel_launch(void* const* d_in, const int* in_sizes, int n_in,
                              void* d_out, int out_size, void* d_ws, size_t ws_size,
                              hipStream_t stream)
{
    const uint4*    x    = (const uint4*)d_in[0];      // (N, 4) int32 rows
    const uint32_t* tw   = (const uint32_t*)d_in[1];   // w^k, k < 2^21
    const uint32_t* ninv = (const uint32_t*)d_in[2];
    uint4*          out  = (uint4*)d_out;

    intt_pass<false><<<dim3(1024), dim3(512), 0, stream>>>(x, out, tw, ninv);
    intt_pass<true ><<<dim3(1024), dim3(512), 0, stream>>>(out, out, tw, ninv);
}